// Round 5
// baseline (413.599 us; speedup 1.0000x reference)
//
#include <hip/hip_runtime.h>
#include <hip/hip_bf16.h>

#define W_WORDS 2048
#define H_DIM   1024
#define C_LAB   32
#define HID_D   512
#define MAXW    12
#define NSPAN   (W_WORDS * MAXW)

typedef __attribute__((ext_vector_type(8))) short bf16x8;
typedef __attribute__((ext_vector_type(4))) float f32x4;

__device__ __forceinline__ unsigned short f2b(float x) {
  union { float f; unsigned int i; } v; v.f = x;
  unsigned int r = v.i + 0x7FFFu + ((v.i >> 16) & 1u);
  return (unsigned short)(r >> 16);
}

#define GLOAD_LDS16(g, l)                                                    \
  __builtin_amdgcn_global_load_lds(                                          \
      (const __attribute__((address_space(1))) unsigned int*)(g),            \
      (__attribute__((address_space(3))) unsigned int*)(l), 16, 0, 0)

// ---------- gather: we_b[m-1] = bf16(hs[t]) (one token per word) ----------
__global__ void gather_k(const float* __restrict__ hs, const int* __restrict__ wm,
                         unsigned short* __restrict__ we_b) {
  int t = blockIdx.x;
  int m = wm[t];
  if (m <= 0) return;
  const float* src = hs + (size_t)t * H_DIM;
  unsigned short* dst = we_b + (size_t)(m - 1) * H_DIM;
  int i = threadIdx.x * 4;
  float4 v = *(const float4*)(src + i);
  ushort4 o = make_ushort4(f2b(v.x), f2b(v.y), f2b(v.z), f2b(v.w));
  *(ushort4*)(dst + i) = o;
}

// ---------- f32 -> bf16 (4 elems/thread; size multiple of 1024) ----------
__global__ void cvt_k(const float* __restrict__ in, unsigned short* __restrict__ out) {
  int i = (blockIdx.x * blockDim.x + threadIdx.x) * 4;
  float4 v = *(const float4*)(in + i);
  ushort4 o = make_ushort4(f2b(v.x), f2b(v.y), f2b(v.z), f2b(v.w));
  *(ushort4*)(out + i) = o;
}

// ---------- all weight transposes in one launch (blockIdx.z selects) ----------
__global__ void transpose_all_k(
    const float* __restrict__ Wt, const float* __restrict__ W1a,
    const float* __restrict__ Wsp1, const float* __restrict__ W1c,
    const float* __restrict__ L, const float* __restrict__ Wsp2,
    unsigned short* __restrict__ WtT, unsigned short* __restrict__ W1aT,
    unsigned short* __restrict__ Wsp1Tc, float* __restrict__ W1cT,
    float* __restrict__ LT, float* __restrict__ Wsp2T) {
  const float* in;
  void* out;
  int R, C, obf;
  switch (blockIdx.z) {
    case 0: in = Wt;   out = WtT;    R = 1024; C = 2048; obf = 1; break;
    case 1: in = W1a;  out = W1aT;   R = 1024; C = 512;  obf = 1; break;
    case 2: in = Wsp1; out = Wsp1Tc; R = 1024; C = 1024; obf = 1; break;
    case 3: in = Wsp1 + 1048576; out = Wsp1Tc + 1048576; R = 1024; C = 1024; obf = 1; break;
    case 4: in = W1c;  out = W1cT;   R = 1024; C = 512;  obf = 0; break;
    case 5: in = L;    out = LT;     R = 32;   C = 1024; obf = 0; break;
    default: in = Wsp2; out = Wsp2T; R = 1024; C = 1024; obf = 0; break;
  }
  int c0 = blockIdx.x * 32, r0 = blockIdx.y * 32;
  if (c0 >= C || r0 >= R) return;
  __shared__ float tile[32][33];
  for (int i = threadIdx.y; i < 32; i += 8)
    tile[i][threadIdx.x] = in[(size_t)(r0 + i) * C + c0 + threadIdx.x];
  __syncthreads();
  if (obf) {
    unsigned short* o = (unsigned short*)out;
    for (int i = threadIdx.y; i < 32; i += 8)
      o[(size_t)(c0 + i) * R + r0 + threadIdx.x] = f2b(tile[threadIdx.x][i]);
  } else {
    float* o = (float*)out;
    for (int i = threadIdx.y; i < 32; i += 8)
      o[(size_t)(c0 + i) * R + r0 + threadIdx.x] = tile[threadIdx.x][i];
  }
}

// ---------- K-parallel small GEMM: out[m][n] = A[m]·B[:,n] + bias ----------
__global__ __launch_bounds__(256) void rgemm_k(int N, int K,
    const float* __restrict__ A, int lda, const float* __restrict__ B, int ldb,
    const float* __restrict__ bias, float* __restrict__ out, int ldc) {
  int m = blockIdx.y;
  int tx = threadIdx.x & 15;
  int ty = threadIdx.x >> 4;
  int n = blockIdx.x * 16 + tx;
  int kpg = K >> 4;
  float acc = 0.f;
  if (n < N) {
    const float* a = A + (size_t)m * lda + ty * kpg;
    const float* b = B + (size_t)(ty * kpg) * ldb + n;
    for (int k = 0; k < kpg; ++k)
      acc = fmaf(a[k], b[(size_t)k * ldb], acc);
  }
  __shared__ float red[16][16];
  red[ty][tx] = acc;
  __syncthreads();
  if (ty == 0 && n < N) {
    float s = 0.f;
#pragma unroll
    for (int q = 0; q < 16; ++q) s += red[q][tx];
    if (bias) s += bias[n];
    out[(size_t)m * ldc + n] = s;
  }
}

// ---------- cv[c] = dot(bsp2, L[c]) ----------
__global__ __launch_bounds__(256) void cv_k(const float* __restrict__ bsp2,
                                            const float* __restrict__ L,
                                            float* __restrict__ cv) {
  int c = blockIdx.x;
  float a = 0.f;
  for (int k = threadIdx.x; k < 1024; k += 256)
    a = fmaf(bsp2[k], L[(size_t)c * 1024 + k], a);
#pragma unroll
  for (int off = 32; off; off >>= 1) a += __shfl_down(a, off);
  __shared__ float red[4];
  if ((threadIdx.x & 63) == 0) red[threadIdx.x >> 6] = a;
  __syncthreads();
  if (threadIdx.x == 0) cv[c] = red[0] + red[1] + red[2] + red[3];
}

// ---------- build K^T[(c*512+d)][h] = l1[c][h] * W1c[h][d] ----------
__global__ void kmat_k(const float* __restrict__ lab, const float* __restrict__ W1cT,
                       unsigned short* __restrict__ KT) {
  int hh = blockIdx.x * 256 + threadIdx.x;
  int row = blockIdx.y;
  int c = row >> 9, d = row & 511;
  float v = lab[(size_t)c * 2048 + 1024 + hh] * W1cT[(size_t)d * 1024 + hh];
  KT[(size_t)row * 1024 + hh] = f2b(v);
}

// ---------- W2padT[n][d] = n<3 ? W2[d][n] : 0   (16 x 512 bf16) ----------
__global__ void w2padt_k(const float* __restrict__ W2, unsigned short* __restrict__ o) {
  int i = blockIdx.x * 256 + threadIdx.x;  // 8192
  int n = i >> 9, d = i & 511;
  o[i] = f2b(n < 3 ? W2[d * 3 + n] : 0.f);
}

// ---------- bf16 MFMA GEMM, 128x128 tile, BT input (m97 structure) ----------
// MODE 0: outF[r*N+c] = val                               (f32)
// MODE 1: c<2048: v+=bias -> out0/out1 bf16 (tok); else outF (UV f32, ld 2048)
template <int MODE>
__global__ __launch_bounds__(256) void gemm_k(
    const unsigned short* __restrict__ A, const unsigned short* __restrict__ BT,
    int N, int K,
    float* __restrict__ outF,
    unsigned short* __restrict__ out0, unsigned short* __restrict__ out1,
    const float* __restrict__ bias) {
  extern __shared__ __align__(16) unsigned short smem[];
  unsigned short* As = smem;
  unsigned short* Bs = smem + 4096;
  int tid = threadIdx.x;
  int lane = tid & 63, wid = tid >> 6;
  int wr = wid >> 1, wc = wid & 1;
  int row0 = blockIdx.y * 128, col0 = blockIdx.x * 128;

  f32x4 zero4 = {0.f, 0.f, 0.f, 0.f};
  f32x4 acc[4][4];
#pragma unroll
  for (int i = 0; i < 4; ++i)
#pragma unroll
    for (int j = 0; j < 4; ++j) acc[i][j] = zero4;

  int sr = tid >> 2;
  int sc = (tid & 3) * 8;
  const unsigned short* gA = A + (size_t)(row0 + sr) * K + sc;
  const unsigned short* gB = BT + (size_t)(col0 + sr) * K + sc;
  unsigned short* lA0 = As + wid * 512;
  unsigned short* lA1 = As + 2048 + wid * 512;
  unsigned short* lB0 = Bs + wid * 512;
  unsigned short* lB1 = Bs + 2048 + wid * 512;

  int hi = lane >> 4;
  int fr = lane & 15;
  int k0 = hi * 8;

  for (int kt = 0; kt < K; kt += 32) {
    GLOAD_LDS16(gA + kt, lA0);
    GLOAD_LDS16(gA + (size_t)64 * K + kt, lA1);
    GLOAD_LDS16(gB + kt, lB0);
    GLOAD_LDS16(gB + (size_t)64 * K + kt, lB1);
    __syncthreads();
    bf16x8 af[4], bfr[4];
#pragma unroll
    for (int i = 0; i < 4; ++i)
      af[i] = *(const bf16x8*)&As[(wr * 64 + i * 16 + fr) * 32 + k0];
#pragma unroll
    for (int i = 0; i < 4; ++i)
      bfr[i] = *(const bf16x8*)&Bs[(wc * 64 + i * 16 + fr) * 32 + k0];
#pragma unroll
    for (int mi = 0; mi < 4; ++mi)
#pragma unroll
      for (int ni = 0; ni < 4; ++ni)
        acc[mi][ni] = __builtin_amdgcn_mfma_f32_16x16x32_bf16(af[mi], bfr[ni], acc[mi][ni], 0, 0, 0);
    __syncthreads();
  }

  int rbase = row0 + wr * 64 + (hi << 2);
  int cbase = col0 + wc * 64 + fr;
#pragma unroll
  for (int mi = 0; mi < 4; ++mi) {
#pragma unroll
    for (int ni = 0; ni < 4; ++ni) {
      int ccol = cbase + ni * 16;
#pragma unroll
      for (int j = 0; j < 4; ++j) {
        int r = rbase + mi * 16 + j;
        float v = acc[mi][ni][j];
        if (MODE == 0) {
          outF[(size_t)r * N + ccol] = v;
        } else {
          if (ccol < 2048) {
            v += bias[ccol];
            if (ccol < 1024) out0[(size_t)r * 1024 + ccol] = f2b(v);
            else             out1[(size_t)r * 1024 + (ccol - 1024)] = f2b(v);
          } else {
            outF[(size_t)r * 2048 + (ccol - 2048)] = v;
          }
        }
      }
    }
  }
}

// ---------- E-GEMM: 256x256 tile, BK=32, 3-buf counted-vmcnt pipeline ----------
// scores partial fused: h = relu(gemm + avec + bvec) -> LDS -> MFMA vs W2padT.
__global__ __launch_bounds__(512, 2) void egemm_k(
    const unsigned short* __restrict__ A,   // t1b [2048][1024]
    const unsigned short* __restrict__ BT,  // KmatT [16384][1024]
    const float* __restrict__ avec,         // [2048][512]
    const float* __restrict__ bvec,         // [32][512], b1 folded
    const unsigned short* __restrict__ w2t, // [16][512]
    float* __restrict__ sPart) {            // [2][2048][96]
  __shared__ __align__(16) unsigned short smem[3 * 16384];  // 96 KB
  int tid = threadIdx.x;
  int lane = tid & 63, wid = tid >> 6;
  int wr = wid >> 2, wc = wid & 3;
  int fr = lane & 15, hi = lane >> 4;

  // XCD-aware remap: each XCD gets 8 contiguous col-panels (B L2-resident)
  int bid = blockIdx.x;             // 512 blocks
  int xcd = bid & 7, slot = bid >> 3;
  int cb = xcd * 8 + (slot >> 3);   // col block 0..63
  int rb = slot & 7;                // row block 0..7
  int row0 = rb * 256, col0 = cb * 256;
  int cc = col0 >> 9, dg0 = col0 & 511;

  // staging: 4 rounds of 16B/thread per K-tile; swizzled global source
  int srow = tid >> 2;                        // 0..127
  int slog = (tid & 3) ^ (srow & 3);          // logical 16B slot
  const unsigned short* gA0 = A + (size_t)(row0 + srow) * 1024 + slog * 8;
  const unsigned short* gA1 = A + (size_t)(row0 + 128 + srow) * 1024 + slog * 8;
  const unsigned short* gB0 = BT + (size_t)(col0 + srow) * 1024 + slog * 8;
  const unsigned short* gB1 = BT + (size_t)(col0 + 128 + srow) * 1024 + slog * 8;

#define EG_STAGE(t)                                                          \
  {                                                                          \
    unsigned short* db = smem + ((t) % 3) * 16384;                           \
    GLOAD_LDS16(gA0 + (t) * 32, db + tid * 8);                               \
    GLOAD_LDS16(gA1 + (t) * 32, db + 4096 + tid * 8);                        \
    GLOAD_LDS16(gB0 + (t) * 32, db + 8192 + tid * 8);                        \
    GLOAD_LDS16(gB1 + (t) * 32, db + 12288 + tid * 8);                       \
  }

  f32x4 zero4 = {0.f, 0.f, 0.f, 0.f};
  f32x4 acc[8][4];
#pragma unroll
  for (int i = 0; i < 8; ++i)
#pragma unroll
    for (int j = 0; j < 4; ++j) acc[i][j] = zero4;

  EG_STAGE(0);
  EG_STAGE(1);
  asm volatile("s_waitcnt vmcnt(4)" ::: "memory");
  __builtin_amdgcn_sched_barrier(0);
  __builtin_amdgcn_s_barrier();

  for (int kt = 0; kt < 32; ++kt) {
    asm volatile("" ::: "memory");
    if (kt + 2 < 32) EG_STAGE(kt + 2);
    const unsigned short* ab = smem + (kt % 3) * 16384;
    bf16x8 af[8], bfr[4];
#pragma unroll
    for (int mi = 0; mi < 8; ++mi) {
      int rl = wr * 128 + mi * 16 + fr;
      af[mi] = *(const bf16x8*)&ab[rl * 32 + ((hi * 8) ^ ((rl & 3) << 3))];
    }
#pragma unroll
    for (int ni = 0; ni < 4; ++ni) {
      int rl = wc * 64 + ni * 16 + fr;
      bfr[ni] = *(const bf16x8*)&ab[8192 + rl * 32 + ((hi * 8) ^ ((rl & 3) << 3))];
    }
    __builtin_amdgcn_s_setprio(1);
#pragma unroll
    for (int mi = 0; mi < 8; ++mi)
#pragma unroll
      for (int ni = 0; ni < 4; ++ni)
        acc[mi][ni] = __builtin_amdgcn_mfma_f32_16x16x32_bf16(af[mi], bfr[ni], acc[mi][ni], 0, 0, 0);
    __builtin_amdgcn_s_setprio(0);
    asm volatile("s_waitcnt vmcnt(4)" ::: "memory");
    __builtin_amdgcn_sched_barrier(0);
    __builtin_amdgcn_s_barrier();
  }
#undef EG_STAGE

  // ---- epilogue: h -> swizzled LDS (two 128-col halves) -> W2 MFMA ----
  f32x4 s0 = zero4, s1 = zero4;
  int R0 = wid * 32;
#pragma unroll
  for (int half = 0; half < 2; ++half) {
    __syncthreads();
    if ((wc >> 1) == half) {
#pragma unroll
      for (int ni = 0; ni < 4; ++ni) {
        int cl = wc * 64 + ni * 16 + fr;          // 0..255
        int cl2 = cl - half * 128;                // 0..127
        int d = dg0 + cl;
        float bv = bvec[cc * 512 + d];
#pragma unroll
        for (int mi = 0; mi < 8; ++mi) {
#pragma unroll
          for (int j = 0; j < 4; ++j) {
            int rl = wr * 128 + mi * 16 + hi * 4 + j;
            float v = acc[mi][ni][j] + avec[(size_t)(row0 + rl) * 512 + d] + bv;
            v = fmaxf(v, 0.f);
            int byte = rl * 256 + ((cl2 * 2) ^ ((rl & 7) << 4));
            *(unsigned short*)((char*)smem + byte) = f2b(v);
          }
        }
      }
    }
    __syncthreads();
#pragma unroll
    for (int ks = 0; ks < 4; ++ks) {
#pragma unroll
      for (int mi2 = 0; mi2 < 2; ++mi2) {
        int rl = R0 + mi2 * 16 + fr;
        int byte = rl * 256 + ((ks * 64 + hi * 16) ^ ((rl & 7) << 4));
        bf16x8 a = *(const bf16x8*)((const char*)smem + byte);
        bf16x8 b = *(const bf16x8*)&w2t[(size_t)fr * 512 + dg0 + half * 128 + ks * 32 + hi * 8];
        if (mi2 == 0) s0 = __builtin_amdgcn_mfma_f32_16x16x32_bf16(a, b, s0, 0, 0, 0);
        else          s1 = __builtin_amdgcn_mfma_f32_16x16x32_bf16(a, b, s1, 0, 0, 0);
      }
    }
  }
  if (fr < 3) {
    float* sp = sPart + ((size_t)(cb & 1) * 2048 + row0 + R0) * 96 + cc * 3 + fr;
#pragma unroll
    for (int j = 0; j < 4; ++j) {
      sp[(size_t)(hi * 4 + j) * 96] = s0[j];
      sp[(size_t)(16 + hi * 4 + j) * 96] = s1[j];
    }
  }
}

// ---------- fold 2 score slices + b2 ----------
__global__ void foldscores_k(const float* __restrict__ part, const float* __restrict__ b2,
                             float* __restrict__ outS) {
  int i = blockIdx.x * 256 + threadIdx.x;  // 196608
  outS[i] = b2[i % 3] + part[i] + part[196608 + i];
}

// ---------- is_start / is_end  (sigmoid(x)>=0.5 <=> x>=0) ----------
__global__ void mask_k(const float* __restrict__ scores, int* __restrict__ is_s,
                       int* __restrict__ is_e) {
  int w = blockIdx.x * blockDim.x + threadIdx.x;
  if (w >= W_WORDS) return;
  int s = 0, e = 0;
  for (int c = 0; c < C_LAB; ++c) {
    s |= (scores[((size_t)w * 32 + c) * 3 + 0] >= 0.f);
    e |= (scores[((size_t)w * 32 + c) * 3 + 1] >= 0.f);
  }
  is_s[w] = s;
  is_e[w] = e;
}

// ---------- fused span: R-chunk in LDS (wave-local) -> MFMA vs MmTb ----------
__global__ __launch_bounds__(256) void spanfuse_k(
    const float* __restrict__ UV, const float* __restrict__ bsp1,
    const unsigned short* __restrict__ MmTb, const float* __restrict__ cvv,
    const int* __restrict__ is_s, const int* __restrict__ is_e,
    float* __restrict__ outIdx, float* __restrict__ outMask,
    float* __restrict__ outLog) {
  __shared__ __align__(16) unsigned short Rs[4096];  // 4 waves x 32 x 32
  int tid = threadIdx.x, lane = tid & 63, w = tid >> 6;
  int fr = lane & 15, hi = lane >> 4;
  int row = lane >> 1, hh = lane & 1;
  int n = blockIdx.x * 128 + w * 32 + row;
  int wi = n / MAXW;
  int j = n - wi * MAXW;
  int er = wi + j;
  int valid = er < W_WORDS;
  int e = valid ? er : (W_WORDS - 1);
  int mask = (valid && is_s[wi] && is_e[e]) ? 1 : 0;
  if (hh == 0) {
    outIdx[2 * n] = (float)wi;
    outIdx[2 * n + 1] = (float)e;
    outMask[n] = (float)mask;
  }
  int si = mask ? wi : 0, ei = mask ? e : 0;
  const float* Up = UV + (size_t)si * 2048 + hh * 16;
  const float* Vp = UV + (size_t)ei * 2048 + 1024 + hh * 16;
  const float* bp = bsp1 + hh * 16;
  unsigned short* wRs = Rs + w * 1024;
  f32x4 zero4 = {0.f, 0.f, 0.f, 0.f};
  f32x4 a00 = zero4, a01 = zero4, a10 = zero4, a11 = zero4;

  for (int kt = 0; kt < 32; ++kt) {
    bf16x8 t0, t1;
#pragma unroll
    for (int q = 0; q < 2; ++q) {
      float4 u0 = *(const float4*)(Up + kt * 32 + q * 8);
      float4 v0 = *(const float4*)(Vp + kt * 32 + q * 8);
      float4 b0 = *(const float4*)(bp + kt * 32 + q * 8);
      float4 u1 = *(const float4*)(Up + kt * 32 + q * 8 + 4);
      float4 v1 = *(const float4*)(Vp + kt * 32 + q * 8 + 4);
      float4 b1 = *(const float4*)(bp + kt * 32 + q * 8 + 4);
      bf16x8 o;
      o[0] = (short)f2b(fmaxf(u0.x + v0.x + b0.x, 0.f));
      o[1] = (short)f2b(fmaxf(u0.y + v0.y + b0.y, 0.f));
      o[2] = (short)f2b(fmaxf(u0.z + v0.z + b0.z, 0.f));
      o[3] = (short)f2b(fmaxf(u0.w + v0.w + b0.w, 0.f));
      o[4] = (short)f2b(fmaxf(u1.x + v1.x + b1.x, 0.f));
      o[5] = (short)f2b(fmaxf(u1.y + v1.y + b1.y, 0.f));
      o[6] = (short)f2b(fmaxf(u1.z + v1.z + b1.z, 0.f));
      o[7] = (short)f2b(fmaxf(u1.w + v1.w + b1.w, 0.f));
      if (q == 0) t0 = o; else t1 = o;
    }
    {
      int s0i = (hh * 2 + 0) ^ (row & 3);
      int s1i = (hh * 2 + 1) ^ (row & 3);
      *(bf16x8*)&wRs[row * 32 + s0i * 8] = t0;
      *(bf16x8*)&wRs[row * 32 + s1i * 8] = t1;
    }
    __syncthreads();
    int r0 = fr, r1 = 16 + fr;
    bf16x8 fa0 = *(const bf16x8*)&wRs[r0 * 32 + ((hi * 8) ^ ((r0 & 3) << 3))];
    bf16x8 fa1 = *(const bf16x8*)&wRs[r1 * 32 + ((hi * 8) ^ ((r1 & 3) << 3))];
    bf16x8 fb0 = *(const bf16x8*)&MmTb[(size_t)fr * 1024 + kt * 32 + hi * 8];
    bf16x8 fb1 = *(const bf16x8*)&MmTb[(size_t)(16 + fr) * 1024 + kt * 32 + hi * 8];
    a00 = __builtin_amdgcn_mfma_f32_16x16x32_bf16(fa0, fb0, a00, 0, 0, 0);
    a01 = __builtin_amdgcn_mfma_f32_16x16x32_bf16(fa0, fb1, a01, 0, 0, 0);
    a10 = __builtin_amdgcn_mfma_f32_16x16x32_bf16(fa1, fb0, a10, 0, 0, 0);
    a11 = __builtin_amdgcn_mfma_f32_16x16x32_bf16(fa1, fb1, a11, 0, 0, 0);
    __syncthreads();
  }
  float c0 = cvv[fr], c1 = cvv[16 + fr];
#pragma unroll
  for (int jj = 0; jj < 4; ++jj) {
    int nn0 = blockIdx.x * 128 + w * 32 + hi * 4 + jj;
    int nn1 = nn0 + 16;
    outLog[(size_t)nn0 * 32 + fr] = a00[jj] + c0;
    outLog[(size_t)nn0 * 32 + 16 + fr] = a01[jj] + c1;
    outLog[(size_t)nn1 * 32 + fr] = a10[jj] + c0;
    outLog[(size_t)nn1 * 32 + 16 + fr] = a11[jj] + c1;
  }
}

extern "C" void kernel_launch(void* const* d_in, const int* in_sizes, int n_in,
                              void* d_out, int out_size, void* d_ws, size_t ws_size,
                              hipStream_t stream) {
  const float* hs   = (const float*)d_in[0];
  const int*   wm   = (const int*)d_in[1];
  const float* L    = (const float*)d_in[2];
  const float* Wt   = (const float*)d_in[3];
  const float* bt   = (const float*)d_in[4];
  const float* Wl   = (const float*)d_in[5];
  const float* bl   = (const float*)d_in[6];
  const float* W1a  = (const float*)d_in[7];
  const float* W1b  = (const float*)d_in[8];
  const float* W1c  = (const float*)d_in[9];
  const float* b1   = (const float*)d_in[10];
  const float* W2   = (const float*)d_in[11];
  const float* b2   = (const float*)d_in[12];
  const float* Wsp1 = (const float*)d_in[13];
  const float* bsp1 = (const float*)d_in[14];
  const float* Wsp2 = (const float*)d_in[15];
  const float* bsp2 = (const float*)d_in[16];

  char* p = (char*)d_ws;
  auto alloc = [&p](size_t bytes) {
    char* r = p;
    p += (bytes + 255) & ~(size_t)255;
    return r;
  };
  unsigned short* we_b   = (unsigned short*)alloc((size_t)2048 * 1024 * 2);
  // WtT and Wsp1Tc MUST be adjacent: merged BT = [WtT ; Wsp1Tc] (4096 x 1024)
  unsigned short* WtT    = (unsigned short*)alloc((size_t)2048 * 1024 * 2);
  unsigned short* Wsp1Tc = (unsigned short*)alloc((size_t)2048 * 1024 * 2);
  unsigned short* t0b    = (unsigned short*)alloc((size_t)2048 * 1024 * 2);
  unsigned short* t1b    = (unsigned short*)alloc((size_t)2048 * 1024 * 2);
  float*          lab    = (float*)alloc((size_t)32 * 2048 * 4);
  unsigned short* W1aT   = (unsigned short*)alloc((size_t)512 * 1024 * 2);
  float*          Avec   = (float*)alloc((size_t)2048 * 512 * 4);
  float*          BvecB  = (float*)alloc((size_t)32 * 512 * 4);
  float*          W1cT   = (float*)alloc((size_t)512 * 1024 * 4);
  unsigned short* KmatT  = (unsigned short*)alloc((size_t)16384 * 1024 * 2);
  float*          sPart  = (float*)alloc((size_t)2 * 2048 * 96 * 4);
  int*            is_s   = (int*)alloc(2048 * 4);
  int*            is_e   = (int*)alloc(2048 * 4);
  float*          UV     = (float*)alloc((size_t)2048 * 2048 * 4);
  float*          LT     = (float*)alloc((size_t)1024 * 32 * 4);
  float*          Wsp2T  = (float*)alloc((size_t)1024 * 1024 * 4);
  float*          MmTf   = (float*)alloc((size_t)32 * 1024 * 4);
  unsigned short* MmTb   = (unsigned short*)alloc((size_t)32 * 1024 * 2);
  float*          cv     = (float*)alloc(32 * 4);
  unsigned short* W2padT = (unsigned short*)alloc((size_t)16 * 512 * 2);

  float* outS    = (float*)d_out;
  float* outIdx  = outS + (size_t)2048 * 32 * 3;
  float* outMask = outIdx + (size_t)NSPAN * 2;
  float* outLog  = outMask + NSPAN;

  gather_k<<<3072, 256, 0, stream>>>(hs, wm, we_b);

  transpose_all_k<<<dim3(64, 32, 7), dim3(32, 8), 0, stream>>>(
      Wt, W1a, Wsp1, W1c, L, Wsp2, WtT, W1aT, Wsp1Tc, W1cT, LT, Wsp2T);

  // lab = L @ Wl + bl   (32 x 2048)
  rgemm_k<<<dim3(128, 32), 256, 0, stream>>>(2048, 1024, L, 1024, Wl, 2048, bl, lab, 2048);
  // BvecB = l0 @ W1b + b1   (32 x 512)
  rgemm_k<<<dim3(32, 32), 256, 0, stream>>>(512, 1024, lab, 2048, W1b, 512, b1, BvecB, 512);
  // MmT = L @ Wsp2^T   (32 x 1024)
  rgemm_k<<<dim3(64, 32), 256, 0, stream>>>(1024, 1024, L, 1024, Wsp2T, 1024, nullptr, MmTf, 1024);
  cv_k<<<32, 256, 0, stream>>>(bsp2, L, cv);
  cvt_k<<<32, 256, 0, stream>>>(MmTf, MmTb);
  w2padt_k<<<32, 256, 0, stream>>>(W2, W2padT);

  // KmatT[(c,d)][h] = l1[c][h] * W1c[h][d]
  kmat_k<<<dim3(4, 16384), 256, 0, stream>>>(lab, W1cT, KmatT);

  // merged: [tok | UV] = we @ [Wt | Wsp1^T-cat]  (N = 4096)
  gemm_k<1><<<dim3(32, 16), 256, 16384, stream>>>(we_b, WtT, 4096, 1024, UV, t0b, t1b, bt);
  // Avec = t0 @ W1a  (2048 x 512 f32)
  gemm_k<0><<<dim3(4, 16), 256, 16384, stream>>>(t0b, W1aT, 512, 1024, Avec, nullptr,
                                                 nullptr, nullptr);
  // E-GEMM + fused scores partials
  egemm_k<<<512, 512, 0, stream>>>(t1b, KmatT, Avec, BvecB, W2padT, sPart);
  foldscores_k<<<768, 256, 0, stream>>>(sPart, b2, outS);
  mask_k<<<8, 256, 0, stream>>>(outS, is_s, is_e);

  // fused span: R chunks + logits
  spanfuse_k<<<192, 256, 0, stream>>>(UV, bsp1, MmTb, cv, is_s, is_e,
                                      outIdx, outMask, outLog);
}

// Round 6
// 307.602 us; speedup vs baseline: 1.3446x; 1.3446x over previous
//
#include <hip/hip_runtime.h>
#include <hip/hip_bf16.h>

#define W_WORDS 2048
#define H_DIM   1024
#define C_LAB   32
#define HID_D   512
#define MAXW    12
#define NSPAN   (W_WORDS * MAXW)

typedef __attribute__((ext_vector_type(8))) short bf16x8;
typedef __attribute__((ext_vector_type(4))) float f32x4;

__device__ __forceinline__ unsigned short f2b(float x) {
  union { float f; unsigned int i; } v; v.f = x;
  unsigned int r = v.i + 0x7FFFu + ((v.i >> 16) & 1u);
  return (unsigned short)(r >> 16);
}

#define GLOAD_LDS16(g, l)                                                    \
  __builtin_amdgcn_global_load_lds(                                          \
      (const __attribute__((address_space(1))) unsigned int*)(g),            \
      (__attribute__((address_space(3))) unsigned int*)(l), 16, 0, 0)

// ---------- gather: we_b[m-1] = bf16(hs[t]) (one token per word) ----------
__global__ void gather_k(const float* __restrict__ hs, const int* __restrict__ wm,
                         unsigned short* __restrict__ we_b) {
  int t = blockIdx.x;
  int m = wm[t];
  if (m <= 0) return;
  const float* src = hs + (size_t)t * H_DIM;
  unsigned short* dst = we_b + (size_t)(m - 1) * H_DIM;
  int i = threadIdx.x * 4;
  float4 v = *(const float4*)(src + i);
  ushort4 o = make_ushort4(f2b(v.x), f2b(v.y), f2b(v.z), f2b(v.w));
  *(ushort4*)(dst + i) = o;
}

// ---------- f32 -> bf16 (4 elems/thread; size multiple of 1024) ----------
__global__ void cvt_k(const float* __restrict__ in, unsigned short* __restrict__ out) {
  int i = (blockIdx.x * blockDim.x + threadIdx.x) * 4;
  float4 v = *(const float4*)(in + i);
  ushort4 o = make_ushort4(f2b(v.x), f2b(v.y), f2b(v.z), f2b(v.w));
  *(ushort4*)(out + i) = o;
}

// ---------- all weight transposes in one launch (blockIdx.z selects) ----------
__global__ void transpose_all_k(
    const float* __restrict__ Wt, const float* __restrict__ W1a,
    const float* __restrict__ Wsp1, const float* __restrict__ W1c,
    const float* __restrict__ L, const float* __restrict__ Wsp2,
    unsigned short* __restrict__ WtT, unsigned short* __restrict__ W1aT,
    unsigned short* __restrict__ Wsp1Tc, float* __restrict__ W1cT,
    float* __restrict__ LT, float* __restrict__ Wsp2T) {
  const float* in;
  void* out;
  int R, C, obf;
  switch (blockIdx.z) {
    case 0: in = Wt;   out = WtT;    R = 1024; C = 2048; obf = 1; break;
    case 1: in = W1a;  out = W1aT;   R = 1024; C = 512;  obf = 1; break;
    case 2: in = Wsp1; out = Wsp1Tc; R = 1024; C = 1024; obf = 1; break;
    case 3: in = Wsp1 + 1048576; out = Wsp1Tc + 1048576; R = 1024; C = 1024; obf = 1; break;
    case 4: in = W1c;  out = W1cT;   R = 1024; C = 512;  obf = 0; break;
    case 5: in = L;    out = LT;     R = 32;   C = 1024; obf = 0; break;
    default: in = Wsp2; out = Wsp2T; R = 1024; C = 1024; obf = 0; break;
  }
  int c0 = blockIdx.x * 32, r0 = blockIdx.y * 32;
  if (c0 >= C || r0 >= R) return;
  __shared__ float tile[32][33];
  for (int i = threadIdx.y; i < 32; i += 8)
    tile[i][threadIdx.x] = in[(size_t)(r0 + i) * C + c0 + threadIdx.x];
  __syncthreads();
  if (obf) {
    unsigned short* o = (unsigned short*)out;
    for (int i = threadIdx.y; i < 32; i += 8)
      o[(size_t)(c0 + i) * R + r0 + threadIdx.x] = f2b(tile[threadIdx.x][i]);
  } else {
    float* o = (float*)out;
    for (int i = threadIdx.y; i < 32; i += 8)
      o[(size_t)(c0 + i) * R + r0 + threadIdx.x] = tile[threadIdx.x][i];
  }
}

// ---------- small GEMM, 8 A-rows per block: out[m][n] = A[m]·B[:,n] + bias ----------
// grid (N/16, M/8), block 256 = 16 cols x 16 k-groups. K must be 1024.
__global__ __launch_bounds__(256) void rgemm8_k(int N, int M,
    const float* __restrict__ A, int lda, const float* __restrict__ B, int ldb,
    const float* __restrict__ bias, float* __restrict__ out, int ldc) {
  __shared__ float Asm[8][1024];
  __shared__ float red[16][16][8];
  int m0 = blockIdx.y * 8;
  for (int idx = threadIdx.x; idx < 8 * 1024; idx += 256) {
    int mm = idx >> 10, kk = idx & 1023;
    Asm[mm][kk] = (m0 + mm < M) ? A[(size_t)(m0 + mm) * lda + kk] : 0.f;
  }
  __syncthreads();
  int tx = threadIdx.x & 15, ty = threadIdx.x >> 4;
  int n = blockIdx.x * 16 + tx;
  float acc[8] = {0.f, 0.f, 0.f, 0.f, 0.f, 0.f, 0.f, 0.f};
  if (n < N) {
    for (int k = ty * 64; k < ty * 64 + 64; ++k) {
      float bv = B[(size_t)k * ldb + n];
#pragma unroll
      for (int mm = 0; mm < 8; ++mm) acc[mm] = fmaf(Asm[mm][k], bv, acc[mm]);
    }
  }
#pragma unroll
  for (int mm = 0; mm < 8; ++mm) red[ty][tx][mm] = acc[mm];
  __syncthreads();
  if (ty < 8 && n < N && m0 + ty < M) {
    float s = 0.f;
#pragma unroll
    for (int q = 0; q < 16; ++q) s += red[q][tx][ty];
    if (bias) s += bias[n];
    out[(size_t)(m0 + ty) * ldc + n] = s;
  }
}

// ---------- cv[c] = dot(bsp2, L[c]) ----------
__global__ __launch_bounds__(256) void cv_k(const float* __restrict__ bsp2,
                                            const float* __restrict__ L,
                                            float* __restrict__ cv) {
  int c = blockIdx.x;
  float a = 0.f;
  for (int k = threadIdx.x; k < 1024; k += 256)
    a = fmaf(bsp2[k], L[(size_t)c * 1024 + k], a);
#pragma unroll
  for (int off = 32; off; off >>= 1) a += __shfl_down(a, off);
  __shared__ float red[4];
  if ((threadIdx.x & 63) == 0) red[threadIdx.x >> 6] = a;
  __syncthreads();
  if (threadIdx.x == 0) cv[c] = red[0] + red[1] + red[2] + red[3];
}

// ---------- build K^T[(c*512+d)][h] = l1[c][h] * W1c[h][d] ----------
__global__ void kmat_k(const float* __restrict__ lab, const float* __restrict__ W1cT,
                       unsigned short* __restrict__ KT) {
  int hh = blockIdx.x * 256 + threadIdx.x;
  int row = blockIdx.y;
  int c = row >> 9, d = row & 511;
  float v = lab[(size_t)c * 2048 + 1024 + hh] * W1cT[(size_t)d * 1024 + hh];
  KT[(size_t)row * 1024 + hh] = f2b(v);
}

// ---------- W2padT[n][d] = n<3 ? W2[d][n] : 0   (16 x 512 bf16) ----------
__global__ void w2padt_k(const float* __restrict__ W2, unsigned short* __restrict__ o) {
  int i = blockIdx.x * 256 + threadIdx.x;  // 8192
  int n = i >> 9, d = i & 511;
  o[i] = f2b(n < 3 ? W2[d * 3 + n] : 0.f);
}

// ---------- bf16 MFMA GEMM, 128x128 tile, BK=64, swizzled LDS ----------
// LDS layout: row-major [128][64] ushort, 16B slot s of row r holds global
// slot s^(r&7)  (both-sides involution: pre-swizzled global source for the
// linear global_load_lds dest, same XOR on ds_read -> conflict-free b128).
// MODE 0: outF[r*N+c] = val                               (f32)
// MODE 1: c<2048: v+=bias -> out0/out1 bf16 (tok); else outF (UV f32, ld 2048)
// MODE 2: 1-D grid + XCD swizzle; h=relu(val+avec+bvec) -> LDS -> MFMA vs w2t
template <int MODE>
__global__ __launch_bounds__(256) void gemm_k(
    const unsigned short* __restrict__ A, const unsigned short* __restrict__ BT,
    int N, int K,
    float* __restrict__ outF,
    unsigned short* __restrict__ out0, unsigned short* __restrict__ out1,
    const float* __restrict__ bias,
    const float* __restrict__ avec, const float* __restrict__ bvec,
    const unsigned short* __restrict__ w2t) {
  __shared__ __align__(16) unsigned short smem[16384];  // 32 KB
  unsigned short* As = smem;
  unsigned short* Bs = smem + 8192;
  int tid = threadIdx.x;
  int lane = tid & 63, wid = tid >> 6;
  int wr = wid >> 1, wc = wid & 1;
  int row0, col0, cbq = 0;
  if (MODE == 2) {
    // bijective XCD swizzle: 2048 blocks = 8 xcd x 16 cb x 16 rb,
    // rb fastest -> 16 blocks sharing a B col-panel run together per XCD.
    int bid = blockIdx.x;
    int xcd = bid & 7, i = bid >> 3;
    int cb = xcd * 16 + (i >> 4);
    int rb = i & 15;
    row0 = rb * 128; col0 = cb * 128; cbq = cb & 3;
  } else {
    row0 = blockIdx.y * 128; col0 = blockIdx.x * 128;
  }

  f32x4 zero4 = {0.f, 0.f, 0.f, 0.f};
  f32x4 acc[4][4];
#pragma unroll
  for (int i = 0; i < 4; ++i)
#pragma unroll
    for (int j = 0; j < 4; ++j) acc[i][j] = zero4;

  // staging: thread -> (row = i2*32 + tid>>3, phys slot = tid&7)
  int srow = tid >> 3;
  int scol = ((tid & 7) ^ (srow & 7)) * 8;  // pre-swizzled global source
  const unsigned short* gA = A + (size_t)(row0 + srow) * K + scol;
  const unsigned short* gB = BT + (size_t)(col0 + srow) * K + scol;
  unsigned short* dA = As + tid * 8;
  unsigned short* dB = Bs + tid * 8;

  int fr = lane & 15, hi = lane >> 4;

  for (int kt = 0; kt < K; kt += 64) {
#pragma unroll
    for (int i2 = 0; i2 < 4; ++i2) {
      GLOAD_LDS16(gA + (size_t)(i2 * 32) * K + kt, dA + i2 * 2048);
      GLOAD_LDS16(gB + (size_t)(i2 * 32) * K + kt, dB + i2 * 2048);
    }
    __syncthreads();
    bf16x8 af[4][2], bfr[4][2];
#pragma unroll
    for (int mi = 0; mi < 4; ++mi) {
      int rl = wr * 64 + mi * 16 + fr;
#pragma unroll
      for (int kk = 0; kk < 2; ++kk)
        af[mi][kk] = *(const bf16x8*)&As[rl * 64 + (((kk << 2) | hi) ^ (rl & 7)) * 8];
    }
#pragma unroll
    for (int ni = 0; ni < 4; ++ni) {
      int rl = wc * 64 + ni * 16 + fr;
#pragma unroll
      for (int kk = 0; kk < 2; ++kk)
        bfr[ni][kk] = *(const bf16x8*)&Bs[rl * 64 + (((kk << 2) | hi) ^ (rl & 7)) * 8];
    }
#pragma unroll
    for (int kk = 0; kk < 2; ++kk)
#pragma unroll
      for (int mi = 0; mi < 4; ++mi)
#pragma unroll
        for (int ni = 0; ni < 4; ++ni)
          acc[mi][ni] = __builtin_amdgcn_mfma_f32_16x16x32_bf16(af[mi][kk], bfr[ni][kk],
                                                                acc[mi][ni], 0, 0, 0);
    __syncthreads();
  }

  // C/D layout: col = lane&15, row = (lane>>4)*4 + j  [m89-verified]
  if (MODE == 2) {
    int cc = col0 >> 9;
    int dg0 = col0 & 511;
#pragma unroll
    for (int mi = 0; mi < 4; ++mi) {
#pragma unroll
      for (int j = 0; j < 4; ++j) {
        int rl = wr * 64 + hi * 4 + mi * 16 + j;
        const float* avp = avec + (size_t)(row0 + rl) * 512 + dg0;
        const float* bvp = bvec + (size_t)cc * 512 + dg0;
#pragma unroll
        for (int ni = 0; ni < 4; ++ni) {
          int cl = wc * 64 + ni * 16 + fr;
          float v = acc[mi][ni][j] + avp[cl] + bvp[cl];
          v = fmaxf(v, 0.f);
          int slot = cl >> 3;
          smem[rl * 128 + (((slot ^ rl) & 7) << 3) + (slot & 8) * 8 + (cl & 7)] = f2b(v);
        }
      }
    }
    __syncthreads();
    f32x4 s0 = zero4, s1 = zero4;
    int r0l = wid * 32 + fr;
    int r1l = wid * 32 + 16 + fr;
#pragma unroll
    for (int kt2 = 0; kt2 < 4; ++kt2) {
      int slot = kt2 * 4 + hi;
      bf16x8 a0 = *(const bf16x8*)&smem[r0l * 128 + (((slot ^ r0l) & 7) << 3) + (slot & 8) * 8];
      bf16x8 a1 = *(const bf16x8*)&smem[r1l * 128 + (((slot ^ r1l) & 7) << 3) + (slot & 8) * 8];
      bf16x8 b = *(const bf16x8*)&w2t[(size_t)fr * 512 + dg0 + kt2 * 32 + hi * 8];
      s0 = __builtin_amdgcn_mfma_f32_16x16x32_bf16(a0, b, s0, 0, 0, 0);
      s1 = __builtin_amdgcn_mfma_f32_16x16x32_bf16(a1, b, s1, 0, 0, 0);
    }
    if (fr < 3) {
      float* sp = outF + ((size_t)cbq * 2048 + row0) * 96 + cc * 3 + fr;
#pragma unroll
      for (int j = 0; j < 4; ++j) {
        sp[(size_t)(wid * 32 + hi * 4 + j) * 96] = s0[j];
        sp[(size_t)(wid * 32 + 16 + hi * 4 + j) * 96] = s1[j];
      }
    }
    return;
  }

  int rbase = row0 + wr * 64 + (hi << 2);
  int cbase = col0 + wc * 64 + fr;
#pragma unroll
  for (int mi = 0; mi < 4; ++mi) {
#pragma unroll
    for (int ni = 0; ni < 4; ++ni) {
      int ccol = cbase + ni * 16;
#pragma unroll
      for (int j = 0; j < 4; ++j) {
        int r = rbase + mi * 16 + j;
        float v = acc[mi][ni][j];
        if (MODE == 0) {
          outF[(size_t)r * N + ccol] = v;
        } else {
          if (ccol < 2048) {
            v += bias[ccol];
            if (ccol < 1024) out0[(size_t)r * 1024 + ccol] = f2b(v);
            else             out1[(size_t)r * 1024 + (ccol - 1024)] = f2b(v);
          } else {
            outF[(size_t)r * 2048 + (ccol - 2048)] = v;
          }
        }
      }
    }
  }
}

// ---------- fold 4 score slices + b2 ----------
__global__ void foldscores_k(const float* __restrict__ part, const float* __restrict__ b2,
                             float* __restrict__ outS) {
  int i = blockIdx.x * 256 + threadIdx.x;  // 196608
  float s = b2[i % 3];
  s += part[i] + part[196608 + i] + part[2 * 196608 + i] + part[3 * 196608 + i];
  outS[i] = s;
}

// ---------- is_start / is_end  (sigmoid(x)>=0.5 <=> x>=0) ----------
__global__ void mask_k(const float* __restrict__ scores, int* __restrict__ is_s,
                       int* __restrict__ is_e) {
  int w = blockIdx.x * blockDim.x + threadIdx.x;
  if (w >= W_WORDS) return;
  int s = 0, e = 0;
  for (int c = 0; c < C_LAB; ++c) {
    s |= (scores[((size_t)w * 32 + c) * 3 + 0] >= 0.f);
    e |= (scores[((size_t)w * 32 + c) * 3 + 1] >= 0.f);
  }
  is_s[w] = s;
  is_e[w] = e;
}

// ---------- fused span: R-chunk in LDS (wave-local) -> MFMA vs MmTb ----------
__global__ __launch_bounds__(256) void spanfuse_k(
    const float* __restrict__ UV, const float* __restrict__ bsp1,
    const unsigned short* __restrict__ MmTb, const float* __restrict__ cvv,
    const int* __restrict__ is_s, const int* __restrict__ is_e,
    float* __restrict__ outIdx, float* __restrict__ outMask,
    float* __restrict__ outLog) {
  __shared__ __align__(16) unsigned short Rs[4096];  // 4 waves x 32 x 32
  int tid = threadIdx.x, lane = tid & 63, w = tid >> 6;
  int fr = lane & 15, hi = lane >> 4;
  int row = lane >> 1, hh = lane & 1;
  int n = blockIdx.x * 128 + w * 32 + row;
  int wi = n / MAXW;
  int j = n - wi * MAXW;
  int er = wi + j;
  int valid = er < W_WORDS;
  int e = valid ? er : (W_WORDS - 1);
  int mask = (valid && is_s[wi] && is_e[e]) ? 1 : 0;
  if (hh == 0) {
    outIdx[2 * n] = (float)wi;
    outIdx[2 * n + 1] = (float)e;
    outMask[n] = (float)mask;
  }
  int si = mask ? wi : 0, ei = mask ? e : 0;
  const float* Up = UV + (size_t)si * 2048 + hh * 16;
  const float* Vp = UV + (size_t)ei * 2048 + 1024 + hh * 16;
  const float* bp = bsp1 + hh * 16;
  unsigned short* wRs = Rs + w * 1024;
  f32x4 zero4 = {0.f, 0.f, 0.f, 0.f};
  f32x4 a00 = zero4, a01 = zero4, a10 = zero4, a11 = zero4;

  for (int kt = 0; kt < 32; ++kt) {
    bf16x8 t0, t1;
#pragma unroll
    for (int q = 0; q < 2; ++q) {
      float4 u0 = *(const float4*)(Up + kt * 32 + q * 8);
      float4 v0 = *(const float4*)(Vp + kt * 32 + q * 8);
      float4 b0 = *(const float4*)(bp + kt * 32 + q * 8);
      float4 u1 = *(const float4*)(Up + kt * 32 + q * 8 + 4);
      float4 v1 = *(const float4*)(Vp + kt * 32 + q * 8 + 4);
      float4 b1 = *(const float4*)(bp + kt * 32 + q * 8 + 4);
      bf16x8 o;
      o[0] = (short)f2b(fmaxf(u0.x + v0.x + b0.x, 0.f));
      o[1] = (short)f2b(fmaxf(u0.y + v0.y + b0.y, 0.f));
      o[2] = (short)f2b(fmaxf(u0.z + v0.z + b0.z, 0.f));
      o[3] = (short)f2b(fmaxf(u0.w + v0.w + b0.w, 0.f));
      o[4] = (short)f2b(fmaxf(u1.x + v1.x + b1.x, 0.f));
      o[5] = (short)f2b(fmaxf(u1.y + v1.y + b1.y, 0.f));
      o[6] = (short)f2b(fmaxf(u1.z + v1.z + b1.z, 0.f));
      o[7] = (short)f2b(fmaxf(u1.w + v1.w + b1.w, 0.f));
      if (q == 0) t0 = o; else t1 = o;
    }
    {
      int s0i = (hh * 2 + 0) ^ (row & 3);
      int s1i = (hh * 2 + 1) ^ (row & 3);
      *(bf16x8*)&wRs[row * 32 + s0i * 8] = t0;
      *(bf16x8*)&wRs[row * 32 + s1i * 8] = t1;
    }
    __syncthreads();
    int r0 = fr, r1 = 16 + fr;
    bf16x8 fa0 = *(const bf16x8*)&wRs[r0 * 32 + ((hi * 8) ^ ((r0 & 3) << 3))];
    bf16x8 fa1 = *(const bf16x8*)&wRs[r1 * 32 + ((hi * 8) ^ ((r1 & 3) << 3))];
    bf16x8 fb0 = *(const bf16x8*)&MmTb[(size_t)fr * 1024 + kt * 32 + hi * 8];
    bf16x8 fb1 = *(const bf16x8*)&MmTb[(size_t)(16 + fr) * 1024 + kt * 32 + hi * 8];
    a00 = __builtin_amdgcn_mfma_f32_16x16x32_bf16(fa0, fb0, a00, 0, 0, 0);
    a01 = __builtin_amdgcn_mfma_f32_16x16x32_bf16(fa0, fb1, a01, 0, 0, 0);
    a10 = __builtin_amdgcn_mfma_f32_16x16x32_bf16(fa1, fb0, a10, 0, 0, 0);
    a11 = __builtin_amdgcn_mfma_f32_16x16x32_bf16(fa1, fb1, a11, 0, 0, 0);
    __syncthreads();
  }
  float c0 = cvv[fr], c1 = cvv[16 + fr];
#pragma unroll
  for (int jj = 0; jj < 4; ++jj) {
    int nn0 = blockIdx.x * 128 + w * 32 + hi * 4 + jj;
    int nn1 = nn0 + 16;
    outLog[(size_t)nn0 * 32 + fr] = a00[jj] + c0;
    outLog[(size_t)nn0 * 32 + 16 + fr] = a01[jj] + c1;
    outLog[(size_t)nn1 * 32 + fr] = a10[jj] + c0;
    outLog[(size_t)nn1 * 32 + 16 + fr] = a11[jj] + c1;
  }
}

extern "C" void kernel_launch(void* const* d_in, const int* in_sizes, int n_in,
                              void* d_out, int out_size, void* d_ws, size_t ws_size,
                              hipStream_t stream) {
  const float* hs   = (const float*)d_in[0];
  const int*   wm   = (const int*)d_in[1];
  const float* L    = (const float*)d_in[2];
  const float* Wt   = (const float*)d_in[3];
  const float* bt   = (const float*)d_in[4];
  const float* Wl   = (const float*)d_in[5];
  const float* bl   = (const float*)d_in[6];
  const float* W1a  = (const float*)d_in[7];
  const float* W1b  = (const float*)d_in[8];
  const float* W1c  = (const float*)d_in[9];
  const float* b1   = (const float*)d_in[10];
  const float* W2   = (const float*)d_in[11];
  const float* b2   = (const float*)d_in[12];
  const float* Wsp1 = (const float*)d_in[13];
  const float* bsp1 = (const float*)d_in[14];
  const float* Wsp2 = (const float*)d_in[15];
  const float* bsp2 = (const float*)d_in[16];

  char* p = (char*)d_ws;
  auto alloc = [&p](size_t bytes) {
    char* r = p;
    p += (bytes + 255) & ~(size_t)255;
    return r;
  };
  unsigned short* we_b   = (unsigned short*)alloc((size_t)2048 * 1024 * 2);
  // WtT and Wsp1Tc MUST be adjacent: merged BT = [WtT ; Wsp1Tc] (4096 x 1024)
  unsigned short* WtT    = (unsigned short*)alloc((size_t)2048 * 1024 * 2);
  unsigned short* Wsp1Tc = (unsigned short*)alloc((size_t)2048 * 1024 * 2);
  unsigned short* t0b    = (unsigned short*)alloc((size_t)2048 * 1024 * 2);
  unsigned short* t1b    = (unsigned short*)alloc((size_t)2048 * 1024 * 2);
  float*          lab    = (float*)alloc((size_t)32 * 2048 * 4);
  unsigned short* W1aT   = (unsigned short*)alloc((size_t)512 * 1024 * 2);
  float*          Avec   = (float*)alloc((size_t)2048 * 512 * 4);
  float*          BvecB  = (float*)alloc((size_t)32 * 512 * 4);
  float*          W1cT   = (float*)alloc((size_t)512 * 1024 * 4);
  unsigned short* KmatT  = (unsigned short*)alloc((size_t)16384 * 1024 * 2);
  float*          sPart  = (float*)alloc((size_t)4 * 2048 * 96 * 4);
  int*            is_s   = (int*)alloc(2048 * 4);
  int*            is_e   = (int*)alloc(2048 * 4);
  float*          UV     = (float*)alloc((size_t)2048 * 2048 * 4);
  float*          LT     = (float*)alloc((size_t)1024 * 32 * 4);
  float*          Wsp2T  = (float*)alloc((size_t)1024 * 1024 * 4);
  float*          MmTf   = (float*)alloc((size_t)32 * 1024 * 4);
  unsigned short* MmTb   = (unsigned short*)alloc((size_t)32 * 1024 * 2);
  float*          cv     = (float*)alloc(32 * 4);
  unsigned short* W2padT = (unsigned short*)alloc((size_t)16 * 512 * 2);

  float* outS    = (float*)d_out;
  float* outIdx  = outS + (size_t)2048 * 32 * 3;
  float* outMask = outIdx + (size_t)NSPAN * 2;
  float* outLog  = outMask + NSPAN;

  gather_k<<<3072, 256, 0, stream>>>(hs, wm, we_b);

  transpose_all_k<<<dim3(64, 32, 7), dim3(32, 8), 0, stream>>>(
      Wt, W1a, Wsp1, W1c, L, Wsp2, WtT, W1aT, Wsp1Tc, W1cT, LT, Wsp2T);

  // lab = L @ Wl + bl   (32 x 2048)
  rgemm8_k<<<dim3(128, 4), 256, 0, stream>>>(2048, 32, L, 1024, Wl, 2048, bl, lab, 2048);
  // BvecB = l0 @ W1b + b1   (32 x 512)
  rgemm8_k<<<dim3(32, 4), 256, 0, stream>>>(512, 32, lab, 2048, W1b, 512, b1, BvecB, 512);
  // MmT = L @ Wsp2^T   (32 x 1024)
  rgemm8_k<<<dim3(64, 4), 256, 0, stream>>>(1024, 32, L, 1024, Wsp2T, 1024, nullptr, MmTf, 1024);
  cv_k<<<32, 256, 0, stream>>>(bsp2, L, cv);
  cvt_k<<<32, 256, 0, stream>>>(MmTf, MmTb);
  w2padt_k<<<32, 256, 0, stream>>>(W2, W2padT);

  // KmatT[(c,d)][h] = l1[c][h] * W1c[h][d]
  kmat_k<<<dim3(4, 16384), 256, 0, stream>>>(lab, W1cT, KmatT);

  // merged: [tok | UV] = we @ [Wt | Wsp1^T-cat]  (N = 4096)
  gemm_k<1><<<dim3(32, 16), 256, 0, stream>>>(we_b, WtT, 4096, 1024, UV, t0b, t1b, bt,
                                              nullptr, nullptr, nullptr);
  // Avec = t0 @ W1a  (2048 x 512 f32)
  gemm_k<0><<<dim3(4, 16), 256, 0, stream>>>(t0b, W1aT, 512, 1024, Avec, nullptr,
                                             nullptr, nullptr, nullptr, nullptr, nullptr);
  // E-GEMM (128² BK=64 swizzled, XCD-clustered 1-D grid) + fused score partials
  gemm_k<2><<<2048, 256, 0, stream>>>(t1b, KmatT, 16384, 1024, sPart, nullptr,
                                      nullptr, nullptr, Avec, BvecB, W2padT);
  foldscores_k<<<768, 256, 0, stream>>>(sPart, b2, outS);
  mask_k<<<8, 256, 0, stream>>>(outS, is_s, is_e);

  // fused span: R chunks + logits
  spanfuse_k<<<192, 256, 0, stream>>>(UV, bsp1, MmTb, cv, is_s, is_e,
                                      outIdx, outMask, outLog);
}

// Round 7
// 229.204 us; speedup vs baseline: 1.8045x; 1.3420x over previous
//
#include <hip/hip_runtime.h>
#include <hip/hip_bf16.h>

#define W_WORDS 2048
#define H_DIM   1024
#define C_LAB   32
#define HID_D   512
#define MAXW    12
#define NSPAN   (W_WORDS * MAXW)

typedef __attribute__((ext_vector_type(8))) short bf16x8;
typedef __attribute__((ext_vector_type(4))) float f32x4;

__device__ __forceinline__ unsigned short f2b(float x) {
  union { float f; unsigned int i; } v; v.f = x;
  unsigned int r = v.i + 0x7FFFu + ((v.i >> 16) & 1u);
  return (unsigned short)(r >> 16);
}
__device__ __forceinline__ float b2f(unsigned short b) {
  union { float f; unsigned int i; } v; v.i = ((unsigned int)b) << 16;
  return v.f;
}

#define GLOAD_LDS16(g, l)                                                    \
  __builtin_amdgcn_global_load_lds(                                          \
      (const __attribute__((address_space(1))) unsigned int*)(g),            \
      (__attribute__((address_space(3))) unsigned int*)(l), 16, 0, 0)

// ---------- gather: we_b[m-1] = bf16(hs[t]) (one token per word) ----------
__global__ void gather_k(const float* __restrict__ hs, const int* __restrict__ wm,
                         unsigned short* __restrict__ we_b) {
  int t = blockIdx.x;
  int m = wm[t];
  if (m <= 0) return;
  const float* src = hs + (size_t)t * H_DIM;
  unsigned short* dst = we_b + (size_t)(m - 1) * H_DIM;
  int i = threadIdx.x * 4;
  float4 v = *(const float4*)(src + i);
  ushort4 o = make_ushort4(f2b(v.x), f2b(v.y), f2b(v.z), f2b(v.w));
  *(ushort4*)(dst + i) = o;
}

// ---------- all weight transposes in one launch (blockIdx.z selects) ----------
__global__ void transpose_all_k(
    const float* __restrict__ Wt, const float* __restrict__ W1a,
    const float* __restrict__ Wsp1, const float* __restrict__ W1c,
    const float* __restrict__ Wsp2,
    unsigned short* __restrict__ WtT, unsigned short* __restrict__ W1aT,
    unsigned short* __restrict__ Wsp1Tc, float* __restrict__ W1cT,
    float* __restrict__ Wsp2T) {
  const float* in;
  void* out;
  int R, C, obf;
  switch (blockIdx.z) {
    case 0: in = Wt;   out = WtT;    R = 1024; C = 2048; obf = 1; break;
    case 1: in = W1a;  out = W1aT;   R = 1024; C = 512;  obf = 1; break;
    case 2: in = Wsp1; out = Wsp1Tc; R = 1024; C = 1024; obf = 1; break;
    case 3: in = Wsp1 + 1048576; out = Wsp1Tc + 1048576; R = 1024; C = 1024; obf = 1; break;
    case 4: in = W1c;  out = W1cT;   R = 1024; C = 512;  obf = 0; break;
    default: in = Wsp2; out = Wsp2T; R = 1024; C = 1024; obf = 0; break;
  }
  int c0 = blockIdx.x * 32, r0 = blockIdx.y * 32;
  if (c0 >= C || r0 >= R) return;
  __shared__ float tile[32][33];
  for (int i = threadIdx.y; i < 32; i += 8)
    tile[i][threadIdx.x] = in[(size_t)(r0 + i) * C + c0 + threadIdx.x];
  __syncthreads();
  if (obf) {
    unsigned short* o = (unsigned short*)out;
    for (int i = threadIdx.y; i < 32; i += 8)
      o[(size_t)(c0 + i) * R + r0 + threadIdx.x] = f2b(tile[threadIdx.x][i]);
  } else {
    float* o = (float*)out;
    for (int i = threadIdx.y; i < 32; i += 8)
      o[(size_t)(c0 + i) * R + r0 + threadIdx.x] = tile[threadIdx.x][i];
  }
}

// ---------- small GEMM body, 8 A-rows per block ----------
__device__ __forceinline__ void rgemm8_body(int N, int M,
    const float* __restrict__ A, int lda, const float* __restrict__ B, int ldb,
    const float* __restrict__ bias, float* __restrict__ out, int ldc) {
  __shared__ float Asm[8][1024];
  __shared__ float red[16][16][8];
  int m0 = blockIdx.y * 8;
  for (int idx = threadIdx.x; idx < 8 * 1024; idx += 256) {
    int mm = idx >> 10, kk = idx & 1023;
    Asm[mm][kk] = (m0 + mm < M) ? A[(size_t)(m0 + mm) * lda + kk] : 0.f;
  }
  __syncthreads();
  int tx = threadIdx.x & 15, ty = threadIdx.x >> 4;
  int n = blockIdx.x * 16 + tx;
  float acc[8] = {0.f, 0.f, 0.f, 0.f, 0.f, 0.f, 0.f, 0.f};
  if (n < N) {
    for (int k = ty * 64; k < ty * 64 + 64; ++k) {
      float bv = B[(size_t)k * ldb + n];
#pragma unroll
      for (int mm = 0; mm < 8; ++mm) acc[mm] = fmaf(Asm[mm][k], bv, acc[mm]);
    }
  }
#pragma unroll
  for (int mm = 0; mm < 8; ++mm) red[ty][tx][mm] = acc[mm];
  __syncthreads();
  if (ty < 8 && n < N && m0 + ty < M) {
    float s = 0.f;
#pragma unroll
    for (int q = 0; q < 16; ++q) s += red[q][tx][ty];
    if (bias) s += bias[n];
    out[(size_t)(m0 + ty) * ldc + n] = s;
  }
}

__global__ __launch_bounds__(256) void rgemm8_k(int N, int M,
    const float* __restrict__ A, int lda, const float* __restrict__ B, int ldb,
    const float* __restrict__ bias, float* __restrict__ out, int ldc) {
  rgemm8_body(N, M, A, lda, B, ldb, bias, out, ldc);
}

// lab = L@Wl+bl (z=0) and MmTf = L@Wsp2T (z=1) in one launch
__global__ __launch_bounds__(256) void rgemm8z_k(
    const float* __restrict__ L, const float* __restrict__ Wl,
    const float* __restrict__ bl, float* __restrict__ lab,
    const float* __restrict__ Wsp2T, float* __restrict__ MmTf) {
  if (blockIdx.z == 0) {
    rgemm8_body(2048, 32, L, 1024, Wl, 2048, bl, lab, 2048);
  } else {
    if (blockIdx.x >= 64) return;
    rgemm8_body(1024, 32, L, 1024, Wsp2T, 1024, nullptr, MmTf, 1024);
  }
}

// ---------- misc small ops in one launch ----------
__global__ __launch_bounds__(256) void misc_k(
    const float* __restrict__ bsp2, const float* __restrict__ L,
    float* __restrict__ cv, const float* __restrict__ MmTf,
    unsigned short* __restrict__ MmTb, const float* __restrict__ W2,
    unsigned short* __restrict__ W2padT, const float* __restrict__ bsp1,
    unsigned short* __restrict__ bsp1b) {
  __shared__ float red[4];
  int b = blockIdx.x;
  if (b < 32) {  // cv[c] = dot(bsp2, L[c])
    int c = b;
    float a = 0.f;
    for (int k = threadIdx.x; k < 1024; k += 256)
      a = fmaf(bsp2[k], L[(size_t)c * 1024 + k], a);
#pragma unroll
    for (int off = 32; off; off >>= 1) a += __shfl_down(a, off);
    if ((threadIdx.x & 63) == 0) red[threadIdx.x >> 6] = a;
    __syncthreads();
    if (threadIdx.x == 0) cv[c] = red[0] + red[1] + red[2] + red[3];
  } else if (b < 64) {  // MmTf -> MmTb bf16
    int i = (b - 32) * 1024 + threadIdx.x * 4;
    float4 v = *(const float4*)(MmTf + i);
    *(ushort4*)(MmTb + i) = make_ushort4(f2b(v.x), f2b(v.y), f2b(v.z), f2b(v.w));
  } else if (b < 96) {  // W2padT[n][d] = n<3 ? W2[d][n] : 0
    int i = (b - 64) * 256 + threadIdx.x;
    int n = i >> 9, d = i & 511;
    W2padT[i] = f2b(n < 3 ? W2[d * 3 + n] : 0.f);
  } else {  // bsp1 -> bsp1b bf16
    int i = threadIdx.x * 4;
    float4 v = *(const float4*)(bsp1 + i);
    *(ushort4*)(bsp1b + i) = make_ushort4(f2b(v.x), f2b(v.y), f2b(v.z), f2b(v.w));
  }
}

// ---------- build K^T[(c*512+d)][h] = l1[c][h] * W1c[h][d], 8 h/thread ----------
__global__ __launch_bounds__(256) void kmat_k(const float* __restrict__ lab,
    const float* __restrict__ W1cT, unsigned short* __restrict__ KT) {
  size_t gid = (size_t)blockIdx.x * 256 + threadIdx.x;  // 2,097,152
  int row = (int)(gid >> 7);
  int h0 = ((int)gid & 127) * 8;
  int c = row >> 9, d = row & 511;
  const float* lp = lab + (size_t)c * 2048 + 1024 + h0;
  const float* wp = W1cT + (size_t)d * 1024 + h0;
  float4 l0 = *(const float4*)lp, l1 = *(const float4*)(lp + 4);
  float4 w0 = *(const float4*)wp, w1 = *(const float4*)(wp + 4);
  bf16x8 o;
  o[0] = (short)f2b(l0.x * w0.x); o[1] = (short)f2b(l0.y * w0.y);
  o[2] = (short)f2b(l0.z * w0.z); o[3] = (short)f2b(l0.w * w0.w);
  o[4] = (short)f2b(l1.x * w1.x); o[5] = (short)f2b(l1.y * w1.y);
  o[6] = (short)f2b(l1.z * w1.z); o[7] = (short)f2b(l1.w * w1.w);
  *(bf16x8*)(KT + (size_t)row * 1024 + h0) = o;
}

// ---------- bf16 MFMA GEMM, 128x128 tile, BK=64, dbuf 2-phase, swizzled ----------
// MODE 0: outF[r*N+c] = val                               (f32)
// MODE 1: c<1024 -> t0b; <2048 -> t1b (both +bias); else out2 bf16 (UVb, ld 2048)
// MODE 2: 1-D grid + XCD swizzle; h=relu(val+avec+bvec) -> LDS -> MFMA vs w2t
template <int MODE>
__global__ __launch_bounds__(256) void gemm_k(
    const unsigned short* __restrict__ A, const unsigned short* __restrict__ BT,
    int N, int K,
    float* __restrict__ outF,
    unsigned short* __restrict__ out0, unsigned short* __restrict__ out1,
    unsigned short* __restrict__ out2,
    const float* __restrict__ bias,
    const float* __restrict__ avec, const float* __restrict__ bvec,
    const unsigned short* __restrict__ w2t) {
  __shared__ __align__(16) unsigned short smem[2][16384];  // 64 KB dbuf
  int tid = threadIdx.x;
  int lane = tid & 63, wid = tid >> 6;
  int wr = wid >> 1, wc = wid & 1;
  int row0, col0, cbq = 0;
  if (MODE == 2) {
    // bijective XCD swizzle: 2048 blocks = 8 xcd x 16 cb x 16 rb (rb fastest)
    int bid = blockIdx.x;
    int xcd = bid & 7, i = bid >> 3;
    int cb = xcd * 16 + (i >> 4);
    int rb = i & 15;
    row0 = rb * 128; col0 = cb * 128; cbq = cb & 3;
  } else {
    row0 = blockIdx.y * 128; col0 = blockIdx.x * 128;
  }

  f32x4 zero4 = {0.f, 0.f, 0.f, 0.f};
  f32x4 acc[4][4];
#pragma unroll
  for (int i = 0; i < 4; ++i)
#pragma unroll
    for (int j = 0; j < 4; ++j) acc[i][j] = zero4;

  // staging: row = i2*32 + tid>>3, phys slot = tid&7, pre-swizzled source
  int srow = tid >> 3;
  int scol = ((tid & 7) ^ (srow & 7)) * 8;
  const unsigned short* gA = A + (size_t)(row0 + srow) * K + scol;
  const unsigned short* gB = BT + (size_t)(col0 + srow) * K + scol;

  int fr = lane & 15, hi = lane >> 4;

  // prologue: stage tile 0 into buf 0
  {
    unsigned short* dA = smem[0] + tid * 8;
    unsigned short* dB = smem[0] + 8192 + tid * 8;
#pragma unroll
    for (int i2 = 0; i2 < 4; ++i2) {
      GLOAD_LDS16(gA + (size_t)(i2 * 32) * K, dA + i2 * 2048);
      GLOAD_LDS16(gB + (size_t)(i2 * 32) * K, dB + i2 * 2048);
    }
  }
  __syncthreads();  // drains vmcnt(0): tile 0 landed

  int nt = K >> 6;
  for (int t = 0; t < nt; ++t) {
    if (t + 1 < nt) {  // issue next tile's loads BEFORE compute (T3 minimum 2-phase)
      unsigned short* dA = smem[(t + 1) & 1] + tid * 8;
      unsigned short* dB = smem[(t + 1) & 1] + 8192 + tid * 8;
      int kt = (t + 1) << 6;
#pragma unroll
      for (int i2 = 0; i2 < 4; ++i2) {
        GLOAD_LDS16(gA + (size_t)(i2 * 32) * K + kt, dA + i2 * 2048);
        GLOAD_LDS16(gB + (size_t)(i2 * 32) * K + kt, dB + i2 * 2048);
      }
    }
    const unsigned short* As = smem[t & 1];
    const unsigned short* Bs = smem[t & 1] + 8192;
    bf16x8 af[4][2], bfr[4][2];
#pragma unroll
    for (int mi = 0; mi < 4; ++mi) {
      int rl = wr * 64 + mi * 16 + fr;
#pragma unroll
      for (int kk = 0; kk < 2; ++kk)
        af[mi][kk] = *(const bf16x8*)&As[rl * 64 + (((kk << 2) | hi) ^ (rl & 7)) * 8];
    }
#pragma unroll
    for (int ni = 0; ni < 4; ++ni) {
      int rl = wc * 64 + ni * 16 + fr;
#pragma unroll
      for (int kk = 0; kk < 2; ++kk)
        bfr[ni][kk] = *(const bf16x8*)&Bs[rl * 64 + (((kk << 2) | hi) ^ (rl & 7)) * 8];
    }
#pragma unroll
    for (int kk = 0; kk < 2; ++kk)
#pragma unroll
      for (int mi = 0; mi < 4; ++mi)
#pragma unroll
        for (int ni = 0; ni < 4; ++ni)
          acc[mi][ni] = __builtin_amdgcn_mfma_f32_16x16x32_bf16(af[mi][kk], bfr[ni][kk],
                                                                acc[mi][ni], 0, 0, 0);
    __syncthreads();  // drains vmcnt(0): next tile landed; this tile's reads done
  }

  // C/D layout: col = lane&15, row = (lane>>4)*4 + j  [m89-verified]
  if (MODE == 2) {
    unsigned short* hsm = &smem[0][0];  // 32 KB h tile
    int cc = col0 >> 9;
    int dg0 = col0 & 511;
#pragma unroll
    for (int mi = 0; mi < 4; ++mi) {
#pragma unroll
      for (int j = 0; j < 4; ++j) {
        int rl = wr * 64 + hi * 4 + mi * 16 + j;
        const float* avp = avec + (size_t)(row0 + rl) * 512 + dg0;
        const float* bvp = bvec + (size_t)cc * 512 + dg0;
#pragma unroll
        for (int ni = 0; ni < 4; ++ni) {
          int cl = wc * 64 + ni * 16 + fr;
          float v = acc[mi][ni][j] + avp[cl] + bvp[cl];
          v = fmaxf(v, 0.f);
          int slot = cl >> 3;
          hsm[rl * 128 + (((slot ^ rl) & 7) << 3) + (slot & 8) * 8 + (cl & 7)] = f2b(v);
        }
      }
    }
    __syncthreads();
    f32x4 s0 = zero4, s1 = zero4;
    int r0l = wid * 32 + fr;
    int r1l = wid * 32 + 16 + fr;
#pragma unroll
    for (int kt2 = 0; kt2 < 4; ++kt2) {
      int slot = kt2 * 4 + hi;
      bf16x8 a0 = *(const bf16x8*)&hsm[r0l * 128 + (((slot ^ r0l) & 7) << 3) + (slot & 8) * 8];
      bf16x8 a1 = *(const bf16x8*)&hsm[r1l * 128 + (((slot ^ r1l) & 7) << 3) + (slot & 8) * 8];
      bf16x8 b = *(const bf16x8*)&w2t[(size_t)fr * 512 + dg0 + kt2 * 32 + hi * 8];
      s0 = __builtin_amdgcn_mfma_f32_16x16x32_bf16(a0, b, s0, 0, 0, 0);
      s1 = __builtin_amdgcn_mfma_f32_16x16x32_bf16(a1, b, s1, 0, 0, 0);
    }
    if (fr < 3) {
      float* sp = outF + ((size_t)cbq * 2048 + row0) * 96 + cc * 3 + fr;
#pragma unroll
      for (int j = 0; j < 4; ++j) {
        sp[(size_t)(wid * 32 + hi * 4 + j) * 96] = s0[j];
        sp[(size_t)(wid * 32 + 16 + hi * 4 + j) * 96] = s1[j];
      }
    }
    return;
  }

  int rbase = row0 + wr * 64 + (hi << 2);
  int cbase = col0 + wc * 64 + fr;
#pragma unroll
  for (int mi = 0; mi < 4; ++mi) {
#pragma unroll
    for (int ni = 0; ni < 4; ++ni) {
      int ccol = cbase + ni * 16;
#pragma unroll
      for (int j = 0; j < 4; ++j) {
        int r = rbase + mi * 16 + j;
        float v = acc[mi][ni][j];
        if (MODE == 0) {
          outF[(size_t)r * N + ccol] = v;
        } else {
          if (ccol < 2048) {
            v += bias[ccol];
            if (ccol < 1024) out0[(size_t)r * 1024 + ccol] = f2b(v);
            else             out1[(size_t)r * 1024 + (ccol - 1024)] = f2b(v);
          } else {
            out2[(size_t)r * 2048 + (ccol - 2048)] = f2b(v);
          }
        }
      }
    }
  }
}

// ---------- fold 4 score slices + b2 ----------
__global__ void foldscores_k(const float* __restrict__ part, const float* __restrict__ b2,
                             float* __restrict__ outS) {
  int i = blockIdx.x * 256 + threadIdx.x;  // 196608
  float s = b2[i % 3];
  s += part[i] + part[196608 + i] + part[2 * 196608 + i] + part[3 * 196608 + i];
  outS[i] = s;
}

// ---------- is_start / is_end  (sigmoid(x)>=0.5 <=> x>=0) ----------
__global__ void mask_k(const float* __restrict__ scores, int* __restrict__ is_s,
                       int* __restrict__ is_e) {
  int w = blockIdx.x * blockDim.x + threadIdx.x;
  if (w >= W_WORDS) return;
  int s = 0, e = 0;
  for (int c = 0; c < C_LAB; ++c) {
    s |= (scores[((size_t)w * 32 + c) * 3 + 0] >= 0.f);
    e |= (scores[((size_t)w * 32 + c) * 3 + 1] >= 0.f);
  }
  is_s[w] = s;
  is_e[w] = e;
}

// ---------- fused span: 16 spans/wave, barrier-free, bf16 UV ----------
__global__ __launch_bounds__(256) void spanfuse_k(
    const unsigned short* __restrict__ UVb, const unsigned short* __restrict__ bsp1b,
    const unsigned short* __restrict__ MmTb, const float* __restrict__ cvv,
    const int* __restrict__ is_s, const int* __restrict__ is_e,
    float* __restrict__ outIdx, float* __restrict__ outMask,
    float* __restrict__ outLog) {
  __shared__ __align__(16) unsigned short Rs[4][16][32];  // 4 KB, wave-local tiles
  int tid = threadIdx.x, lane = tid & 63, w = tid >> 6;
  int fr = lane & 15, hi = lane >> 4;
  int row = lane >> 2, q = lane & 3;
  int n = blockIdx.x * 64 + w * 16 + row;
  int wi = n / MAXW;
  int j = n - wi * MAXW;
  int er = wi + j;
  int valid = er < W_WORDS;
  int e = valid ? er : (W_WORDS - 1);
  int mask = (valid && is_s[wi] && is_e[e]) ? 1 : 0;
  if (q == 0) {
    outIdx[2 * n] = (float)wi;
    outIdx[2 * n + 1] = (float)e;
    outMask[n] = (float)mask;
  }
  int si = mask ? wi : 0, ei = mask ? e : 0;
  const unsigned short* Up = UVb + (size_t)si * 2048 + q * 8;
  const unsigned short* Vp = UVb + (size_t)ei * 2048 + 1024 + q * 8;
  const unsigned short* bp = bsp1b + q * 8;
  unsigned short* wRs = &Rs[w][0][0];
  f32x4 zero4 = {0.f, 0.f, 0.f, 0.f};
  f32x4 a0 = zero4, a1 = zero4;

  bf16x8 u = *(const bf16x8*)Up;
  bf16x8 v = *(const bf16x8*)Vp;
  bf16x8 bb = *(const bf16x8*)bp;
  bf16x8 fb0 = *(const bf16x8*)&MmTb[(size_t)fr * 1024 + hi * 8];
  bf16x8 fb1 = *(const bf16x8*)&MmTb[(size_t)(16 + fr) * 1024 + hi * 8];

  for (int kt = 0; kt < 32; ++kt) {
    // issue next-iteration loads first (overlap with VALU+LDS+MFMA below)
    int kn = ((kt + 1) & 31) * 32;
    bf16x8 un = *(const bf16x8*)(Up + kn);
    bf16x8 vn = *(const bf16x8*)(Vp + kn);
    bf16x8 bn = *(const bf16x8*)(bp + kn);
    bf16x8 f0n = *(const bf16x8*)&MmTb[(size_t)fr * 1024 + kn + hi * 8];
    bf16x8 f1n = *(const bf16x8*)&MmTb[(size_t)(16 + fr) * 1024 + kn + hi * 8];

    bf16x8 o;
#pragma unroll
    for (int i = 0; i < 8; ++i) {
      float s = b2f((unsigned short)u[i]) + b2f((unsigned short)v[i]) +
                b2f((unsigned short)bb[i]);
      o[i] = (short)f2b(fmaxf(s, 0.f));
    }
    *(bf16x8*)&wRs[row * 32 + (q ^ (row & 3)) * 8] = o;
    asm volatile("s_waitcnt lgkmcnt(0)" ::: "memory");  // wave-local write->read fence
    bf16x8 fa = *(const bf16x8*)&wRs[fr * 32 + ((hi ^ (fr & 3)) & 3) * 8];
    a0 = __builtin_amdgcn_mfma_f32_16x16x32_bf16(fa, fb0, a0, 0, 0, 0);
    a1 = __builtin_amdgcn_mfma_f32_16x16x32_bf16(fa, fb1, a1, 0, 0, 0);
    u = un; v = vn; bb = bn; fb0 = f0n; fb1 = f1n;
  }

  int n0 = blockIdx.x * 64 + w * 16;
  float c0 = cvv[fr], c1 = cvv[16 + fr];
#pragma unroll
  for (int jj = 0; jj < 4; ++jj) {
    int nn = n0 + hi * 4 + jj;
    outLog[(size_t)nn * 32 + fr] = a0[jj] + c0;
    outLog[(size_t)nn * 32 + 16 + fr] = a1[jj] + c1;
  }
}

extern "C" void kernel_launch(void* const* d_in, const int* in_sizes, int n_in,
                              void* d_out, int out_size, void* d_ws, size_t ws_size,
                              hipStream_t stream) {
  const float* hs   = (const float*)d_in[0];
  const int*   wm   = (const int*)d_in[1];
  const float* L    = (const float*)d_in[2];
  const float* Wt   = (const float*)d_in[3];
  const float* bt   = (const float*)d_in[4];
  const float* Wl   = (const float*)d_in[5];
  const float* bl   = (const float*)d_in[6];
  const float* W1a  = (const float*)d_in[7];
  const float* W1b  = (const float*)d_in[8];
  const float* W1c  = (const float*)d_in[9];
  const float* b1   = (const float*)d_in[10];
  const float* W2   = (const float*)d_in[11];
  const float* b2   = (const float*)d_in[12];
  const float* Wsp1 = (const float*)d_in[13];
  const float* bsp1 = (const float*)d_in[14];
  const float* Wsp2 = (const float*)d_in[15];
  const float* bsp2 = (const float*)d_in[16];

  char* p = (char*)d_ws;
  auto alloc = [&p](size_t bytes) {
    char* r = p;
    p += (bytes + 255) & ~(size_t)255;
    return r;
  };
  unsigned short* we_b   = (unsigned short*)alloc((size_t)2048 * 1024 * 2);
  // WtT and Wsp1Tc MUST be adjacent: merged BT = [WtT ; Wsp1Tc] (4096 x 1024)
  unsigned short* WtT    = (unsigned short*)alloc((size_t)2048 * 1024 * 2);
  unsigned short* Wsp1Tc = (unsigned short*)alloc((size_t)2048 * 1024 * 2);
  unsigned short* t0b    = (unsigned short*)alloc((size_t)2048 * 1024 * 2);
  unsigned short* t1b    = (unsigned short*)alloc((size_t)2048 * 1024 * 2);
  float*          lab    = (float*)alloc((size_t)32 * 2048 * 4);
  unsigned short* W1aT   = (unsigned short*)alloc((size_t)512 * 1024 * 2);
  float*          Avec   = (float*)alloc((size_t)2048 * 512 * 4);
  float*          BvecB  = (float*)alloc((size_t)32 * 512 * 4);
  float*          W1cT   = (float*)alloc((size_t)512 * 1024 * 4);
  unsigned short* KmatT  = (unsigned short*)alloc((size_t)16384 * 1024 * 2);
  float*          sPart  = (float*)alloc((size_t)4 * 2048 * 96 * 4);
  int*            is_s   = (int*)alloc(2048 * 4);
  int*            is_e   = (int*)alloc(2048 * 4);
  unsigned short* UVb    = (unsigned short*)alloc((size_t)2048 * 2048 * 2);
  float*          Wsp2T  = (float*)alloc((size_t)1024 * 1024 * 4);
  float*          MmTf   = (float*)alloc((size_t)32 * 1024 * 4);
  unsigned short* MmTb   = (unsigned short*)alloc((size_t)32 * 1024 * 2);
  float*          cv     = (float*)alloc(32 * 4);
  unsigned short* W2padT = (unsigned short*)alloc((size_t)16 * 512 * 2);
  unsigned short* bsp1b  = (unsigned short*)alloc((size_t)1024 * 2);

  float* outS    = (float*)d_out;
  float* outIdx  = outS + (size_t)2048 * 32 * 3;
  float* outMask = outIdx + (size_t)NSPAN * 2;
  float* outLog  = outMask + NSPAN;

  gather_k<<<3072, 256, 0, stream>>>(hs, wm, we_b);

  transpose_all_k<<<dim3(64, 32, 6), dim3(32, 8), 0, stream>>>(
      Wt, W1a, Wsp1, W1c, Wsp2, WtT, W1aT, Wsp1Tc, W1cT, Wsp2T);

  // lab = L@Wl+bl and MmTf = L@Wsp2T in one launch
  rgemm8z_k<<<dim3(128, 4, 2), 256, 0, stream>>>(L, Wl, bl, lab, Wsp2T, MmTf);
  // BvecB = l0 @ W1b + b1   (32 x 512)
  rgemm8_k<<<dim3(32, 4), 256, 0, stream>>>(512, 32, lab, 2048, W1b, 512, b1, BvecB, 512);
  // cv, MmTb, W2padT, bsp1b in one launch
  misc_k<<<97, 256, 0, stream>>>(bsp2, L, cv, MmTf, MmTb, W2, W2padT, bsp1, bsp1b);

  // KmatT[(c,d)][h] = l1[c][h] * W1c[h][d]
  kmat_k<<<8192, 256, 0, stream>>>(lab, W1cT, KmatT);

  // merged: [tok | UV] = we @ [Wt | Wsp1^T-cat]  (N = 4096), UV out bf16
  gemm_k<1><<<dim3(32, 16), 256, 0, stream>>>(we_b, WtT, 4096, 1024, nullptr, t0b, t1b,
                                              UVb, bt, nullptr, nullptr, nullptr);
  // Avec = t0 @ W1a  (2048 x 512 f32)
  gemm_k<0><<<dim3(4, 16), 256, 0, stream>>>(t0b, W1aT, 512, 1024, Avec, nullptr, nullptr,
                                             nullptr, nullptr, nullptr, nullptr, nullptr);
  // E-GEMM (128² BK=64 dbuf 2-phase, XCD-clustered) + fused score partials
  gemm_k<2><<<2048, 256, 0, stream>>>(t1b, KmatT, 16384, 1024, sPart, nullptr, nullptr,
                                      nullptr, nullptr, Avec, BvecB, W2padT);
  foldscores_k<<<768, 256, 0, stream>>>(sPart, b2, outS);
  mask_k<<<8, 256, 0, stream>>>(outS, is_s, is_e);

  // fused span: 16 spans/wave, barrier-free
  spanfuse_k<<<384, 256, 0, stream>>>(UVb, bsp1b, MmTb, cv, is_s, is_e,
                                      outIdx, outMask, outLog);
}